// Round 2
// baseline (471.148 us; speedup 1.0000x reference)
//
#include <hip/hip_runtime.h>
#include <hip/hip_bf16.h>

// Problem constants
#define BATCH   65536
#define HW      28
#define OHW     26
#define FEAT    676     // 26*26
#define KPAD    704     // 22 chunks of 32
#define FPAD    712     // ushort row stride = 356 dwords -> 89 dword-quads (odd mod 8), 2-way A-read conflicts only
#define HID     200
#define NPAD    208     // 13 tiles of 16
#define NCLS    10
#define MT      16      // images per block
#define NTHREADS 256    // 4 waves
#define NBLOCKS (BATCH / MT)   // 4096

typedef __attribute__((ext_vector_type(8))) __bf16 bf16x8;
typedef __attribute__((ext_vector_type(4))) float  f32x4;

// w1 (676x200 f32, row-major) -> w1T bf16 [NPAD][KPAD], zero-padded.
__global__ __launch_bounds__(256) void prep_w1t(const float* __restrict__ w1,
                                                unsigned short* __restrict__ w1t) {
  int idx = blockIdx.x * 256 + threadIdx.x;
  if (idx >= NPAD * KPAD) return;
  int n = idx / KPAD;
  int k = idx - n * KPAD;
  float v = (n < HID && k < FEAT) ? w1[k * HID + n] : 0.f;
  __hip_bfloat16 h = __float2bfloat16(v);
  w1t[idx] = __builtin_bit_cast(unsigned short, h);
}

// Per-wave GEMM1 n-slice + in-register GEMM2 partials.
// A: lane holds feat[m = lane&15][k = (lane>>4)*8 + j]  (16x16x32 bf16, m90-m97 verified)
// B: lane holds w1t[n = nt*16 + (lane&15)][same k]      (B^T layout)
// C/D: col(n) = lane&15, row(m) = (lane>>4)*4 + reg     (m89/m91 verified)
template<int NT0, int NT>
__device__ __forceinline__ void gemm_epi(
    const unsigned short (*feat)[FPAD], const unsigned short* __restrict__ w1t,
    const float* __restrict__ b1, const float* __restrict__ w2,
    float (*pbuf)[MT][NCLS], int wave, int ln, int qd) {
  f32x4 acc[NT];
  #pragma unroll
  for (int t = 0; t < NT; ++t) acc[t] = (f32x4){0.f, 0.f, 0.f, 0.f};

  const int koff = qd * 8;
  for (int kc = 0; kc < 22; ++kc) {
    const int k0 = kc * 32 + koff;
    bf16x8 a = *(const bf16x8*)&feat[ln][k0];
    #pragma unroll
    for (int t = 0; t < NT; ++t) {
      bf16x8 b = *(const bf16x8*)(w1t + (size_t)((NT0 + t) * 16 + ln) * KPAD + k0);
      acc[t] = __builtin_amdgcn_mfma_f32_16x16x32_bf16(a, b, acc[t], 0, 0, 0);
    }
  }

  // hidden = relu(acc + b1); partial[m][c] += hidden * w2[n][c], n private per lane
  float partial[4][NCLS];
  #pragma unroll
  for (int rr = 0; rr < 4; ++rr)
    #pragma unroll
    for (int c = 0; c < NCLS; ++c) partial[rr][c] = 0.f;

  #pragma unroll
  for (int t = 0; t < NT; ++t) {
    const int n = (NT0 + t) * 16 + ln;
    if (n < HID) {                       // nt==12, ln>=8 -> padded cols, skip
      const float bias = b1[n];          // L1-resident
      const float2* w2r = (const float2*)(w2 + n * NCLS);   // 40B stride, 8B aligned
      float2 wv[5];
      #pragma unroll
      for (int p = 0; p < 5; ++p) wv[p] = w2r[p];
      #pragma unroll
      for (int rr = 0; rr < 4; ++rr) {
        const float h = fmaxf(acc[t][rr] + bias, 0.f);
        #pragma unroll
        for (int p = 0; p < 5; ++p) {
          partial[rr][2 * p]     += h * wv[p].x;
          partial[rr][2 * p + 1] += h * wv[p].y;
        }
      }
    }
  }

  // reduce over ln (16 lanes share one m-row set per qd segment)
  #pragma unroll
  for (int rr = 0; rr < 4; ++rr) {
    #pragma unroll
    for (int c = 0; c < NCLS; ++c) {
      float v = partial[rr][c];
      v += __shfl_xor(v, 1, 16);
      v += __shfl_xor(v, 2, 16);
      v += __shfl_xor(v, 4, 16);
      v += __shfl_xor(v, 8, 16);
      if (ln == 0) pbuf[wave][qd * 4 + rr][c] = v;
    }
  }
}

__global__ __launch_bounds__(NTHREADS) void fused_fwd(
    const float* __restrict__ x, const float* __restrict__ cwp,
    const unsigned short* __restrict__ w1t, const float* __restrict__ b1,
    const float* __restrict__ w2, const float* __restrict__ b2,
    float* __restrict__ out) {
  __shared__ unsigned short feat[MT][FPAD];   // 22,784 B
  __shared__ float pbuf[4][MT][NCLS];         //  2,560 B  -> ~25.4 KB total, 6 blocks/CU

  const int tid  = threadIdx.x;
  const int wave = tid >> 6;
  const int lane = tid & 63;

  // zero feat k-pad dwords [338,352) per row (ushort cols 676..703)
  {
    unsigned int* fp = (unsigned int*)&feat[0][0];
    for (int i = tid; i < MT * 14; i += NTHREADS) {
      int m = i / 14, d = 338 + (i % 14);
      fp[m * (FPAD / 2) + d] = 0;
    }
  }

  float cw[9];
  #pragma unroll
  for (int t = 0; t < 9; ++t) cw[t] = cwp[t];

  // ---- Phase 1: conv 3x3 VALID, fp32 compute, bf16 -> LDS ----
  // task = (image m, out-row i); 16*26 = 416 tasks over 256 threads.
  for (int task = tid; task < MT * OHW; task += NTHREADS) {
    int m = task & (MT - 1);
    int i = task >> 4;
    long gm = (long)blockIdx.x * MT + m;
    const float4* xr = (const float4*)(x + gm * (HW * HW));
    float r[3][HW];
    #pragma unroll
    for (int di = 0; di < 3; ++di) {
      #pragma unroll
      for (int q = 0; q < 7; ++q) {
        float4 v = xr[(i + di) * 7 + q];
        r[di][q * 4 + 0] = v.x; r[di][q * 4 + 1] = v.y;
        r[di][q * 4 + 2] = v.z; r[di][q * 4 + 3] = v.w;
      }
    }
    unsigned int* dst = (unsigned int*)&feat[m][i * OHW];  // i*26 even -> dword aligned
    #pragma unroll
    for (int jp = 0; jp < 13; ++jp) {
      float s0 = 0.f, s1 = 0.f;
      #pragma unroll
      for (int di = 0; di < 3; ++di) {
        #pragma unroll
        for (int dj = 0; dj < 3; ++dj) {
          s0 += cw[di * 3 + dj] * r[di][2 * jp + dj];
          s1 += cw[di * 3 + dj] * r[di][2 * jp + 1 + dj];
        }
      }
      __hip_bfloat16 h0 = __float2bfloat16(s0);
      __hip_bfloat16 h1 = __float2bfloat16(s1);
      dst[jp] = (unsigned int)__builtin_bit_cast(unsigned short, h0)
              | ((unsigned int)__builtin_bit_cast(unsigned short, h1) << 16);
    }
  }
  __syncthreads();

  // ---- Phase 2+3: per-wave GEMM1 n-slice + in-register GEMM2 partials ----
  const int ln = lane & 15;
  const int qd = lane >> 4;
  switch (wave) {
    case 0: gemm_epi<0, 4>(feat, w1t, b1, w2, pbuf, wave, ln, qd); break;
    case 1: gemm_epi<4, 3>(feat, w1t, b1, w2, pbuf, wave, ln, qd); break;
    case 2: gemm_epi<7, 3>(feat, w1t, b1, w2, pbuf, wave, ln, qd); break;
    default: gemm_epi<10, 3>(feat, w1t, b1, w2, pbuf, wave, ln, qd); break;
  }
  __syncthreads();

  // ---- Final: combine 4 wave partials + b2, coalesced store ----
  if (tid < MT * NCLS) {
    int m = tid / NCLS;
    int c = tid - m * NCLS;
    float s = pbuf[0][m][c] + pbuf[1][m][c] + pbuf[2][m][c] + pbuf[3][m][c] + b2[c];
    out[(size_t)blockIdx.x * (MT * NCLS) + tid] = s;
  }
}

extern "C" void kernel_launch(void* const* d_in, const int* in_sizes, int n_in,
                              void* d_out, int out_size, void* d_ws, size_t ws_size,
                              hipStream_t stream) {
  const float* x  = (const float*)d_in[0];
  const float* cw = (const float*)d_in[1];
  const float* w1 = (const float*)d_in[2];
  const float* b1 = (const float*)d_in[3];
  const float* w2 = (const float*)d_in[4];
  const float* b2 = (const float*)d_in[5];
  unsigned short* w1t = (unsigned short*)d_ws;   // needs 208*704*2 = 292,864 B
  float* out = (float*)d_out;

  const int prep_elems = NPAD * KPAD;
  hipLaunchKernelGGL(prep_w1t, dim3((prep_elems + 255) / 256), dim3(256), 0, stream,
                     w1, w1t);
  hipLaunchKernelGGL(fused_fwd, dim3(NBLOCKS), dim3(NTHREADS), 0, stream,
                     x, cw, w1t, b1, w2, b2, out);
}